// Round 19
// baseline (368.657 us; speedup 1.0000x reference)
//
#include <hip/hip_runtime.h>
#include <stdint.h>

// BitStackLinear. Device dtypes: x,u,vt = float32 (harness upcasts fp16),
// qweight = int32, out = float32.
// Pipeline: prep (build_w body THEN convert_x tail, sequential within each
// block — one dispatch, no co-residency pathology) ; 256x256 4-phase
// Gray-code bf16 GEMM (R13 schedule: one barrier/phase, vmcnt(4), trailing
// reads after MFMA, T2 chunk-XOR swizzle, setprio, XCD swizzle).
// Bracketing: GEMM 231(R9/R13)-238(R10)-251(R18)-269(R11)-445(R12);
// prep: unfused 122 < split-fused 140 < parity-fused 235. Deep staging
// regressed (LDS-write pileup), reverted.

#define W_BITS 4
#define OUT_F  4096
#define IN_F   4096
#define K_RANK 16
#define M_TOT  8192
#define QW_PER_BIT (OUT_F * IN_F / 8)

typedef __attribute__((ext_vector_type(8))) short bf16x8;
typedef __attribute__((ext_vector_type(4))) float f32x4;

__device__ __forceinline__ unsigned short f2bf(float f) {
  union { float f; unsigned int u; } c; c.f = f;
  unsigned int r = c.u + 0x7fffu + ((c.u >> 16) & 1u);  // RNE
  return (unsigned short)(r >> 16);
}

// ---------------------------------------------------------------------------
// Kernel 1 (prep): per block, build_w tile FIRST, then convert an X chunk.
// Globally this behaves like two back-to-back dispatches minus one launch
// boundary (build is VALU-bound, convert is BW-bound; both full-grid).
// ---------------------------------------------------------------------------
#define TO 4

__global__ __launch_bounds__(256) void prep_bw_cvt(
    const float* __restrict__ X,
    const int*   __restrict__ qw,
    const float* __restrict__ u,
    const float* __restrict__ vt,
    unsigned short* __restrict__ xb,   // [M_TOT][IN_F] bf16
    unsigned short* __restrict__ w)    // [OUT_F][IN_F] bf16
{
  // ---- part 1: build_w (identical indexing to the proven kernel) ----
  {
    const int tid = blockIdx.x * 256 + threadIdx.x;
    const int ig  = tid & 511;
    const int i0  = ig << 3;
    const int ob  = (tid >> 9) << 2;

    float acc[TO][8];
    #pragma unroll
    for (int t = 0; t < TO; ++t)
      #pragma unroll
      for (int ii = 0; ii < 8; ++ii) acc[t][ii] = 0.0f;

    #pragma unroll
    for (int bit = 0; bit < W_BITS; ++bit) {
      float lr[TO][8];
      #pragma unroll
      for (int t = 0; t < TO; ++t)
        #pragma unroll
        for (int ii = 0; ii < 8; ++ii) lr[t][ii] = 0.0f;

      const float* vbase = vt + (size_t)(bit * K_RANK) * IN_F + i0;
      const float* ubase = u + (size_t)(bit * OUT_F + ob) * K_RANK;

      #pragma unroll
      for (int k = 0; k < K_RANK; ++k) {
        const f32x4 v0 = *reinterpret_cast<const f32x4*>(vbase + (size_t)k * IN_F);
        const f32x4 v1 = *reinterpret_cast<const f32x4*>(vbase + (size_t)k * IN_F + 4);
        float vf[8] = {v0[0], v0[1], v0[2], v0[3], v1[0], v1[1], v1[2], v1[3]};
        #pragma unroll
        for (int t = 0; t < TO; ++t) {
          const float uk = ubase[t * K_RANK + k];
          #pragma unroll
          for (int ii = 0; ii < 8; ++ii) lr[t][ii] += uk * vf[ii];
        }
      }

      #pragma unroll
      for (int t = 0; t < TO; ++t) {
        const int q = qw[(size_t)bit * QW_PER_BIT + (size_t)(ob + t) * (IN_F / 8) + ig];
        #pragma unroll
        for (int ii = 0; ii < 8; ++ii)
          acc[t][ii] += ((q >> ii) & 1) ? lr[t][ii] : -lr[t][ii];
      }
    }

    #pragma unroll
    for (int t = 0; t < TO; ++t) {
      unsigned short o8[8];
      #pragma unroll
      for (int ii = 0; ii < 8; ++ii) o8[ii] = f2bf(acc[t][ii]);
      *reinterpret_cast<uint4*>(w + (size_t)(ob + t) * IN_F + i0) =
          *reinterpret_cast<const uint4*>(o8);
    }
  }

  // ---- part 2: convert_x chunk (grid-stride, same coverage as before) ----
  {
    const int n8 = M_TOT * IN_F / 8;
    const int stride = 2048 * 256;
    for (int i = blockIdx.x * 256 + threadIdx.x; i < n8; i += stride) {
      const f32x4 a = *reinterpret_cast<const f32x4*>(X + (size_t)i * 8);
      const f32x4 b = *reinterpret_cast<const f32x4*>(X + (size_t)i * 8 + 4);
      unsigned short o8[8] = {f2bf(a[0]), f2bf(a[1]), f2bf(a[2]), f2bf(a[3]),
                              f2bf(b[0]), f2bf(b[1]), f2bf(b[2]), f2bf(b[3])};
      *reinterpret_cast<uint4*>(xb + (size_t)i * 8) = *reinterpret_cast<const uint4*>(o8);
    }
  }
}

// ---------------------------------------------------------------------------
// build_w (standalone, fallback path only)
// ---------------------------------------------------------------------------
__global__ __launch_bounds__(256) void build_w(
    const int*   __restrict__ qw,
    const float* __restrict__ u,
    const float* __restrict__ vt,
    unsigned short* __restrict__ w)
{
  const int tid = blockIdx.x * 256 + threadIdx.x;
  const int ig  = tid & 511;
  const int i0  = ig << 3;
  const int ob  = (tid >> 9) << 2;

  float acc[TO][8];
  #pragma unroll
  for (int t = 0; t < TO; ++t)
    #pragma unroll
    for (int ii = 0; ii < 8; ++ii) acc[t][ii] = 0.0f;

  #pragma unroll
  for (int bit = 0; bit < W_BITS; ++bit) {
    float lr[TO][8];
    #pragma unroll
    for (int t = 0; t < TO; ++t)
      #pragma unroll
      for (int ii = 0; ii < 8; ++ii) lr[t][ii] = 0.0f;

    const float* vbase = vt + (size_t)(bit * K_RANK) * IN_F + i0;
    const float* ubase = u + (size_t)(bit * OUT_F + ob) * K_RANK;

    #pragma unroll
    for (int k = 0; k < K_RANK; ++k) {
      const f32x4 v0 = *reinterpret_cast<const f32x4*>(vbase + (size_t)k * IN_F);
      const f32x4 v1 = *reinterpret_cast<const f32x4*>(vbase + (size_t)k * IN_F + 4);
      float vf[8] = {v0[0], v0[1], v0[2], v0[3], v1[0], v1[1], v1[2], v1[3]};
      #pragma unroll
      for (int t = 0; t < TO; ++t) {
        const float uk = ubase[t * K_RANK + k];
        #pragma unroll
        for (int ii = 0; ii < 8; ++ii) lr[t][ii] += uk * vf[ii];
      }
    }

    #pragma unroll
    for (int t = 0; t < TO; ++t) {
      const int q = qw[(size_t)bit * QW_PER_BIT + (size_t)(ob + t) * (IN_F / 8) + ig];
      #pragma unroll
      for (int ii = 0; ii < 8; ++ii)
        acc[t][ii] += ((q >> ii) & 1) ? lr[t][ii] : -lr[t][ii];
    }
  }

  #pragma unroll
  for (int t = 0; t < TO; ++t) {
    unsigned short o8[8];
    #pragma unroll
    for (int ii = 0; ii < 8; ++ii) o8[ii] = f2bf(acc[t][ii]);
    *reinterpret_cast<uint4*>(w + (size_t)(ob + t) * IN_F + i0) =
        *reinterpret_cast<const uint4*>(o8);
  }
}

// ---------------------------------------------------------------------------
// Kernel 2 (main, R13): 256x256 tile, BK=64, 512 thr = 8 waves (2Mx4N).
// Gray-code quadrants (0,0)->(0,1)->(1,1)->(1,0); B-reg role swap P/Q.
// Per phase (ONE barrier): STAGE ; vmcnt(4)+barrier ; lgkm(0) ; setprio+MFMA ;
// trailing ds_reads for the NEXT phase. Stage order ph1:B0' ph2:A0' ph3:B1'
// ph4:A1'; every phase-end read targets the G_{p-2} group (landed by vmcnt(4)
// + barrier). WAR separated by >= 2 barriers everywhere.
// ---------------------------------------------------------------------------
__device__ __forceinline__ void gll16(unsigned short* lds, const unsigned short* g) {
  __builtin_amdgcn_global_load_lds(
      (const __attribute__((address_space(1))) unsigned int*)g,
      (__attribute__((address_space(3))) unsigned int*)lds,
      16, 0, 0);
}

__global__ __launch_bounds__(512, 2) void gemm_256(
    const unsigned short* __restrict__ X,    // [M_TOT][IN_F] bf16
    const unsigned short* __restrict__ W,    // [OUT_F][IN_F] bf16
    float* __restrict__ out)                 // [M_TOT][OUT_F] f32
{
  __shared__ __align__(16) unsigned short Al[2][256][64];   // 64 KiB
  __shared__ __align__(16) unsigned short Bl[2][256][64];   // 64 KiB

  const int bid = blockIdx.x;                   // 512 blocks (32 x 16)
  const int swz = (bid & 7) * 64 + (bid >> 3);  // XCD-bijective (512%8==0)
  const int bm = swz >> 4;                      // 0..31
  const int bn = swz & 15;                      // 0..15

  const int tid  = threadIdx.x;
  const int lane = tid & 63;
  const int wid  = tid >> 6;     // 0..7
  const int wm   = wid >> 2;     // 0..1
  const int wn   = wid & 3;      // 0..3

  // staging: row sr, physical chunk tid&7 holds logical chunk (tid&7)^(sr&7)
  const int sr = tid >> 3;                                  // 0..63
  const int sc = (((tid & 7) ^ (sr & 7)) << 3);             // shorts

  const unsigned short* Abase = X + (size_t)(bm * 256 + sr) * IN_F + sc;
  const unsigned short* Bbase = W + (size_t)(bn * 256 + sr) * IN_F + sc;
  unsigned short* Alt = &Al[0][0][0] + tid * 8;   // linear dest
  unsigned short* Blt = &Bl[0][0][0] + tid * 8;

  // fragment reads (mfma_f32_16x16x32_bf16: lane l -> row l&15, k=(l>>4)*8..+7)
  const int fr  = lane & 15;
  const int sw0 = (((lane >> 4) ^ (fr & 7)) << 3);   // shorts; ks=1 adds ^32
  const int aRow = (wm * 16 + fr) * 64;
  const int bRow = (wn * 16 + fr) * 64;
  const unsigned short* Ar = &Al[0][0][0];
  const unsigned short* Br = &Bl[0][0][0];

  f32x4 acc[8][4];
  #pragma unroll
  for (int f = 0; f < 8; ++f)
    #pragma unroll
    for (int g = 0; g < 4; ++g)
      acc[f][g] = (f32x4){0.f, 0.f, 0.f, 0.f};

  // half-tile h: 0 = A rows 0-127, 1 = A rows 128-255, 2 = B-h0, 3 = B-h1
#define STAGE(buf, h, tn_) do {                                                        \
    const unsigned short* gs_ = ((h) < 2 ? Abase : Bbase)                              \
        + (size_t)(((h) & 1) * 128) * IN_F + (size_t)(tn_) * 64;                       \
    unsigned short* ld_ = ((h) < 2 ? Alt : Blt) + (buf) * 16384 + ((h) & 1) * 8192;    \
    gll16(ld_, gs_);                                                                   \
    gll16(ld_ + 4096, gs_ + (size_t)64 * IN_F);                                        \
  } while (0)

#define WAITBAR() do {                                                                 \
    asm volatile("s_waitcnt vmcnt(4)" ::: "memory");                                   \
    __builtin_amdgcn_s_barrier();                                                      \
    __builtin_amdgcn_sched_barrier(0);                                                 \
  } while (0)

#define LGKMW(n_) do {                                                                 \
    asm volatile("s_waitcnt lgkmcnt(" #n_ ")" ::: "memory");                           \
    __builtin_amdgcn_sched_barrier(0);                                                 \
  } while (0)

#define SB() __builtin_amdgcn_sched_barrier(0)

#define RD_A(base_, mh_, f_, ks_)                                                      \
    aF[f_][ks_] = *reinterpret_cast<const bf16x8*>(                                    \
        Ar + (base_) + ((mh_) * 4 + (f_)) * 2048 + aRow + (((ks_) * 32) ^ sw0))

#define RD_B(dst_, base_, nh_, g_, ks_)                                                \
    dst_[g_][ks_] = *reinterpret_cast<const bf16x8*>(                                  \
        Br + (base_) + ((nh_) * 2 + (g_)) * 4096 + bRow + (((ks_) * 32) ^ sw0))

#define MF(mh_, nh_, f_, g_, ks_, bsrc_)                                               \
    acc[(mh_) * 4 + (f_)][(nh_) * 2 + (g_)] = __builtin_amdgcn_mfma_f32_16x16x32_bf16( \
        aF[f_][ks_], bsrc_[g_][ks_], acc[(mh_) * 4 + (f_)][(nh_) * 2 + (g_)], 0, 0, 0)

#define MF4(mh_, nh_, f_, bsrc_) do {                                                  \
    MF(mh_, nh_, f_, 0, 0, bsrc_); MF(mh_, nh_, f_, 0, 1, bsrc_);                      \
    MF(mh_, nh_, f_, 1, 0, bsrc_); MF(mh_, nh_, f_, 1, 1, bsrc_); } while (0)

#define KTILE(P_, Q_, CC_, OO_, tn_) do {                                              \
    const int cb_ = (CC_) * 16384, ob_ = (OO_) * 16384;                                \
    /* ph1: MFMA (0,0)=A0xP; trailing reads Q<-B1(cur). Stage B0'(next). */            \
    STAGE(OO_, 2, tn_);                                                                \
    WAITBAR();                                                                         \
    LGKMW(0);                                                                          \
    __builtin_amdgcn_s_setprio(1);                                                     \
    MF4(0, 0, 0, P_); MF4(0, 0, 1, P_); MF4(0, 0, 2, P_); MF4(0, 0, 3, P_);            \
    __builtin_amdgcn_s_setprio(0);                                                     \
    SB();                                                                              \
    RD_B(Q_, cb_, 1, 0, 0); RD_B(Q_, cb_, 1, 0, 1);                                    \
    RD_B(Q_, cb_, 1, 1, 0); RD_B(Q_, cb_, 1, 1, 1);                                    \
    /* ph2: MFMA (0,1)=A0xQ; trailing reads aF<-A1(cur). Stage A0'(next). */           \
    STAGE(OO_, 0, tn_);                                                                \
    WAITBAR();                                                                         \
    LGKMW(0);                                                                          \
    __builtin_amdgcn_s_setprio(1);                                                     \
    MF4(0, 1, 0, Q_); MF4(0, 1, 1, Q_); MF4(0, 1, 2, Q_); MF4(0, 1, 3, Q_);            \
    __builtin_amdgcn_s_setprio(0);                                                     \
    SB();                                                                              \
    RD_A(cb_, 1, 0, 0); RD_A(cb_, 1, 0, 1); RD_A(cb_, 1, 1, 0); RD_A(cb_, 1, 1, 1);    \
    RD_A(cb_, 1, 2, 0); RD_A(cb_, 1, 2, 1); RD_A(cb_, 1, 3, 0); RD_A(cb_, 1, 3, 1);    \
    /* ph3: MFMA (1,1)=A1xQ; trailing reads Q<-B0(next). Stage B1'(next). */           \
    STAGE(OO_, 3, tn_);                                                                \
    WAITBAR();                                                                         \
    LGKMW(0);                                                                          \
    __builtin_amdgcn_s_setprio(1);                                                     \
    MF4(1, 1, 0, Q_); MF4(1, 1, 1, Q_); MF4(1, 1, 2, Q_); MF4(1, 1, 3, Q_);            \
    __builtin_amdgcn_s_setprio(0);                                                     \
    SB();                                                                              \
    RD_B(Q_, ob_, 0, 0, 0); RD_B(Q_, ob_, 0, 0, 1);                                    \
    RD_B(Q_, ob_, 0, 1, 0); RD_B(Q_, ob_, 0, 1, 1);                                    \
    /* ph4: MFMA (1,0)=A1xP; trailing reads aF<-A0(next). Stage A1'(next). */          \
    STAGE(OO_, 1, tn_);                                                                \
    WAITBAR();                                                                         \
    LGKMW(0);                                                                          \
    __builtin_amdgcn_s_setprio(1);                                                     \
    MF4(1, 0, 0, P_); MF4(1, 0, 1, P_); MF4(1, 0, 2, P_); MF4(1, 0, 3, P_);            \
    __builtin_amdgcn_s_setprio(0);                                                     \
    SB();                                                                              \
    RD_A(ob_, 0, 0, 0); RD_A(ob_, 0, 0, 1); RD_A(ob_, 0, 1, 0); RD_A(ob_, 0, 1, 1);    \
    RD_A(ob_, 0, 2, 0); RD_A(ob_, 0, 2, 1); RD_A(ob_, 0, 3, 0); RD_A(ob_, 0, 3, 1);    \
  } while (0)

  // prologue: stage tile 0 (A0, B0, B1, A1); vmcnt(4) -> A0,B0 landed;
  // barrier; pre-read aF<-A0, bF0<-B0.
  STAGE(0, 0, 0);
  STAGE(0, 2, 0);
  STAGE(0, 3, 0);
  STAGE(0, 1, 0);
  asm volatile("s_waitcnt vmcnt(4)" ::: "memory");
  __builtin_amdgcn_s_barrier();
  __builtin_amdgcn_sched_barrier(0);

  bf16x8 aF[4][2], bF0[2][2], bF1[2][2];
  RD_A(0, 0, 0, 0); RD_A(0, 0, 0, 1); RD_A(0, 0, 1, 0); RD_A(0, 0, 1, 1);
  RD_A(0, 0, 2, 0); RD_A(0, 0, 2, 1); RD_A(0, 0, 3, 0); RD_A(0, 0, 3, 1);
  RD_B(bF0, 0, 0, 0, 0); RD_B(bF0, 0, 0, 0, 1);
  RD_B(bF0, 0, 0, 1, 0); RD_B(bF0, 0, 0, 1, 1);

  #pragma unroll 1
  for (int Th = 0; Th < 32; ++Th) {
    const int T0 = 2 * Th;
    const int tnA = T0 + 1;                          // <= 63 always
    const int tnB = (T0 + 2 < 64) ? T0 + 2 : 63;     // clamp (dup, unread)
    KTILE(bF0, bF1, 0, 1, tnA);
    KTILE(bF1, bF0, 1, 0, tnB);
  }

  asm volatile("s_waitcnt vmcnt(0) lgkmcnt(0)" ::: "memory");

  // epilogue: D mapping col = lane&15, row = (lane>>4)*4 + j [m89]
  const int rsub = (lane >> 4) << 2;
  #pragma unroll
  for (int f = 0; f < 8; ++f) {
    const int row = bm * 256 + (f * 2 + wm) * 16 + rsub;
    #pragma unroll
    for (int g = 0; g < 4; ++g) {
      const int col = bn * 256 + (g * 4 + wn) * 16 + (lane & 15);
      float* op = out + (size_t)row * OUT_F + col;
      #pragma unroll
      for (int j = 0; j < 4; ++j) op[(size_t)j * OUT_F] = acc[f][g][j];
    }
  }
#undef STAGE
#undef WAITBAR
#undef LGKMW
#undef SB
#undef RD_A
#undef RD_B
#undef MF
#undef MF4
#undef KTILE
}

// ---------------------------------------------------------------------------
// Fallback GEMM (round-4, passing): A f32 reg-staged+converted. ws < 96MB only.
// ---------------------------------------------------------------------------
#define BM 128
#define BN 128
#define BK 32

__device__ __forceinline__ uint4 cvt8(f32x4 a, f32x4 b) {
  unsigned short o8[8] = {f2bf(a[0]), f2bf(a[1]), f2bf(a[2]), f2bf(a[3]),
                          f2bf(b[0]), f2bf(b[1]), f2bf(b[2]), f2bf(b[3])};
  return *reinterpret_cast<const uint4*>(o8);
}

__global__ __launch_bounds__(256) void gemm_f32stage(
    const float* __restrict__ X,
    const unsigned short* __restrict__ W,
    float* __restrict__ out)
{
  __shared__ __align__(16) unsigned short As[BM * BK];
  __shared__ __align__(16) unsigned short Bs[BN * BK];

  const int nbn = OUT_F / BN;
  const int cpx = (M_TOT / BM) * nbn / 8;
  const int bid = blockIdx.x;
  const int swz = (bid & 7) * cpx + (bid >> 3);
  const int bm = swz / nbn;
  const int bn = swz % nbn;

  const int tid  = threadIdx.x;
  const int lane = tid & 63;
  const int wid  = tid >> 6;
  const int wm   = wid >> 1;
  const int wn   = wid & 1;
  const int srow = tid >> 2;
  const int scol = (tid & 3) << 3;

  const float*          Ag = X + (size_t)(bm * BM + srow) * IN_F + scol;
  const unsigned short* Bg = W + (size_t)(bn * BN + srow) * IN_F + scol;

  const int fr = lane & 15;
  const int fk = (lane >> 4) << 3;

  f32x4 acc[4][4];
  #pragma unroll
  for (int m = 0; m < 4; ++m)
    #pragma unroll
    for (int n = 0; n < 4; ++n)
      acc[m][n] = (f32x4){0.f, 0.f, 0.f, 0.f};

  for (int k0 = 0; k0 < IN_F; k0 += BK) {
    const f32x4 a0a = *reinterpret_cast<const f32x4*>(Ag + k0);
    const f32x4 a0b = *reinterpret_cast<const f32x4*>(Ag + k0 + 4);
    const f32x4 a1a = *reinterpret_cast<const f32x4*>(Ag + (size_t)64 * IN_F + k0);
    const f32x4 a1b = *reinterpret_cast<const f32x4*>(Ag + (size_t)64 * IN_F + k0 + 4);
    const uint4 b0  = *reinterpret_cast<const uint4*>(Bg + k0);
    const uint4 b1  = *reinterpret_cast<const uint4*>(Bg + (size_t)64 * IN_F + k0);

    __syncthreads();
    *reinterpret_cast<uint4*>(As + tid * 8)        = cvt8(a0a, a0b);
    *reinterpret_cast<uint4*>(As + 2048 + tid * 8) = cvt8(a1a, a1b);
    *reinterpret_cast<uint4*>(Bs + tid * 8)        = b0;
    *reinterpret_cast<uint4*>(Bs + 2048 + tid * 8) = b1;
    __syncthreads();

    bf16x8 af[4], bfv[4];
    #pragma unroll
    for (int m = 0; m < 4; ++m)
      af[m] = *reinterpret_cast<const bf16x8*>(&As[(wm * 64 + m * 16 + fr) * BK + fk]);
    #pragma unroll
    for (int n = 0; n < 4; ++n)
      bfv[n] = *reinterpret_cast<const bf16x8*>(&Bs[(wn * 64 + n * 16 + fr) * BK + fk]);

    #pragma unroll
    for (int m = 0; m < 4; ++m)
      #pragma unroll
      for (int n = 0; n < 4; ++n)
        acc[m][n] = __builtin_amdgcn_mfma_f32_16x16x32_bf16(af[m], bfv[n], acc[m][n], 0, 0, 0);
  }

  const int rsub = (lane >> 4) << 2;
  #pragma unroll
  for (int m = 0; m < 4; ++m) {
    #pragma unroll
    for (int n = 0; n < 4; ++n) {
      const int col = bn * BN + wn * 64 + n * 16 + (lane & 15);
      #pragma unroll
      for (int j = 0; j < 4; ++j) {
        const int row = bm * BM + wm * 64 + m * 16 + rsub + j;
        out[(size_t)row * OUT_F + col] = acc[m][n][j];
      }
    }
  }
}

// ---------------------------------------------------------------------------
extern "C" void kernel_launch(void* const* d_in, const int* in_sizes, int n_in,
                              void* d_out, int out_size, void* d_ws, size_t ws_size,
                              hipStream_t stream) {
  (void)in_sizes; (void)n_in; (void)out_size;

  const float* x  = (const float*)d_in[0];
  const int*   qw = (const int*)d_in[1];
  const float* u  = (const float*)d_in[2];
  const float* vt = (const float*)d_in[3];
  float* out = (float*)d_out;

  unsigned short* w = (unsigned short*)d_ws;                   // 32 MB
  const size_t W_BYTES  = (size_t)OUT_F * IN_F * 2;
  const size_t XB_BYTES = (size_t)M_TOT * IN_F * 2;

  if (ws_size >= W_BYTES + XB_BYTES) {
    unsigned short* xb = w + (size_t)OUT_F * IN_F;
    prep_bw_cvt<<<dim3(2048), dim3(256), 0, stream>>>(x, qw, u, vt, xb, w);
    gemm_256<<<dim3(512), dim3(512), 0, stream>>>(xb, w, out);
  } else {
    build_w<<<dim3(2048), dim3(256), 0, stream>>>(qw, u, vt, w);
    gemm_f32stage<<<dim3(2048), dim3(256), 0, stream>>>(x, w, out);
  }
}

// Round 20
// 359.554 us; speedup vs baseline: 1.0253x; 1.0253x over previous
//
#include <hip/hip_runtime.h>
#include <stdint.h>

// BitStackLinear. Device dtypes: x,u,vt = float32 (harness upcasts fp16),
// qweight = int32, out = float32.
// Pipeline: build_w ; convert_x (unfused — bracketed best) ; 256x256 GEMM,
// R20 = m201-style wait discipline on the verified base:
//   reads at PHASE HEAD for same-phase MFMA; vmcnt(6) ONCE per K-tile (ph4);
//   two barriers/phase; stage slots ph1:B0(T+1)->OO, ph2:A0(T+2)->CC,
//   ph3:B1(T+2)->CC, ph4:A1(T+2)->CC.
// Ledger: ph4(T) vmcnt(6) leaves {A0(T+2),B1(T+2),A1(T+2)} outstanding ->
// forces B0(T+1)@ph1(T) and all earlier (A0/B1/A1(T+1)@ph2-4(T-1)) => all
// reads during T+1 hit forced regions (collective via ph4's barriers).
// WAR: every stage lands >=1 closing-barrier after the region's last read
// drained (A0: read ph1-head/stage ph2; B1: ph2/ph3; A1: ph3/ph4; B0:
// ph1(T-1)/ph1(T)). Prologue = steady-state prefix [A0,B1,A1,B0](0) +
// [A0,B1,A1](1), vmcnt(6) forces tile 0. Tail clamps write dead regions only.

#define W_BITS 4
#define OUT_F  4096
#define IN_F   4096
#define K_RANK 16
#define M_TOT  8192
#define QW_PER_BIT (OUT_F * IN_F / 8)

typedef __attribute__((ext_vector_type(8))) short bf16x8;
typedef __attribute__((ext_vector_type(4))) float f32x4;

__device__ __forceinline__ unsigned short f2bf(float f) {
  union { float f; unsigned int u; } c; c.f = f;
  unsigned int r = c.u + 0x7fffu + ((c.u >> 16) & 1u);  // RNE
  return (unsigned short)(r >> 16);
}

// ---------------------------------------------------------------------------
// Kernel 0: X f32 -> bf16
// ---------------------------------------------------------------------------
__global__ __launch_bounds__(256) void convert_x(
    const float* __restrict__ X, unsigned short* __restrict__ Xb, int n8)
{
  const int stride = gridDim.x * blockDim.x;
  for (int i = blockIdx.x * blockDim.x + threadIdx.x; i < n8; i += stride) {
    const f32x4 a = *reinterpret_cast<const f32x4*>(X + (size_t)i * 8);
    const f32x4 b = *reinterpret_cast<const f32x4*>(X + (size_t)i * 8 + 4);
    unsigned short o8[8] = {f2bf(a[0]), f2bf(a[1]), f2bf(a[2]), f2bf(a[3]),
                            f2bf(b[0]), f2bf(b[1]), f2bf(b[2]), f2bf(b[3])};
    *reinterpret_cast<uint4*>(Xb + (size_t)i * 8) = *reinterpret_cast<const uint4*>(o8);
  }
}

// ---------------------------------------------------------------------------
// Kernel 1: w[o][i] = sum_bit sign * (u[bit] @ vt[bit])[o][i]; w bf16.
// ---------------------------------------------------------------------------
#define TO 4

__global__ __launch_bounds__(256) void build_w(
    const int*   __restrict__ qw,
    const float* __restrict__ u,
    const float* __restrict__ vt,
    unsigned short* __restrict__ w)
{
  const int tid = blockIdx.x * 256 + threadIdx.x;
  const int ig  = tid & 511;
  const int i0  = ig << 3;
  const int ob  = (tid >> 9) << 2;

  float acc[TO][8];
  #pragma unroll
  for (int t = 0; t < TO; ++t)
    #pragma unroll
    for (int ii = 0; ii < 8; ++ii) acc[t][ii] = 0.0f;

  #pragma unroll
  for (int bit = 0; bit < W_BITS; ++bit) {
    float lr[TO][8];
    #pragma unroll
    for (int t = 0; t < TO; ++t)
      #pragma unroll
      for (int ii = 0; ii < 8; ++ii) lr[t][ii] = 0.0f;

    const float* vbase = vt + (size_t)(bit * K_RANK) * IN_F + i0;
    const float* ubase = u + (size_t)(bit * OUT_F + ob) * K_RANK;

    #pragma unroll
    for (int k = 0; k < K_RANK; ++k) {
      const f32x4 v0 = *reinterpret_cast<const f32x4*>(vbase + (size_t)k * IN_F);
      const f32x4 v1 = *reinterpret_cast<const f32x4*>(vbase + (size_t)k * IN_F + 4);
      float vf[8] = {v0[0], v0[1], v0[2], v0[3], v1[0], v1[1], v1[2], v1[3]};
      #pragma unroll
      for (int t = 0; t < TO; ++t) {
        const float uk = ubase[t * K_RANK + k];
        #pragma unroll
        for (int ii = 0; ii < 8; ++ii) lr[t][ii] += uk * vf[ii];
      }
    }

    #pragma unroll
    for (int t = 0; t < TO; ++t) {
      const int q = qw[(size_t)bit * QW_PER_BIT + (size_t)(ob + t) * (IN_F / 8) + ig];
      #pragma unroll
      for (int ii = 0; ii < 8; ++ii)
        acc[t][ii] += ((q >> ii) & 1) ? lr[t][ii] : -lr[t][ii];
    }
  }

  #pragma unroll
  for (int t = 0; t < TO; ++t) {
    unsigned short o8[8];
    #pragma unroll
    for (int ii = 0; ii < 8; ++ii) o8[ii] = f2bf(acc[t][ii]);
    *reinterpret_cast<uint4*>(w + (size_t)(ob + t) * IN_F + i0) =
        *reinterpret_cast<const uint4*>(o8);
  }
}

// ---------------------------------------------------------------------------
// Kernel 2 (main): 256x256 tile, BK=64, 512 thr = 8 waves (2Mx4N).
// Gray-code quadrants (0,0)@ph1 -> (0,1)@ph2 -> (1,1)@ph3 -> (1,0)@ph4.
// Per phase: [head ds_reads for THIS phase] ; STAGE ; (ph4: vmcnt(6)) ;
// barrier ; lgkm(0) ; setprio+16 MFMA ; barrier.
// ---------------------------------------------------------------------------
__device__ __forceinline__ void gll16(unsigned short* lds, const unsigned short* g) {
  __builtin_amdgcn_global_load_lds(
      (const __attribute__((address_space(1))) unsigned int*)g,
      (__attribute__((address_space(3))) unsigned int*)lds,
      16, 0, 0);
}

__global__ __launch_bounds__(512, 2) void gemm_256(
    const unsigned short* __restrict__ X,    // [M_TOT][IN_F] bf16
    const unsigned short* __restrict__ W,    // [OUT_F][IN_F] bf16
    float* __restrict__ out)                 // [M_TOT][OUT_F] f32
{
  __shared__ __align__(16) unsigned short Al[2][256][64];   // 64 KiB
  __shared__ __align__(16) unsigned short Bl[2][256][64];   // 64 KiB

  const int bid = blockIdx.x;                   // 512 blocks (32 x 16)
  const int swz = (bid & 7) * 64 + (bid >> 3);  // XCD-bijective (512%8==0)
  const int bm = swz >> 4;                      // 0..31
  const int bn = swz & 15;                      // 0..15

  const int tid  = threadIdx.x;
  const int lane = tid & 63;
  const int wid  = tid >> 6;     // 0..7
  const int wm   = wid >> 2;     // 0..1
  const int wn   = wid & 3;      // 0..3

  // staging: row sr, physical chunk tid&7 holds logical chunk (tid&7)^(sr&7)
  const int sr = tid >> 3;                                  // 0..63
  const int sc = (((tid & 7) ^ (sr & 7)) << 3);             // shorts

  const unsigned short* Abase = X + (size_t)(bm * 256 + sr) * IN_F + sc;
  const unsigned short* Bbase = W + (size_t)(bn * 256 + sr) * IN_F + sc;
  unsigned short* Alt = &Al[0][0][0] + tid * 8;   // linear dest
  unsigned short* Blt = &Bl[0][0][0] + tid * 8;

  // fragment reads (mfma_f32_16x16x32_bf16: lane l -> row l&15, k=(l>>4)*8..+7)
  const int fr  = lane & 15;
  const int sw0 = (((lane >> 4) ^ (fr & 7)) << 3);   // shorts; ks=1 adds ^32
  const int aRow = (wm * 16 + fr) * 64;
  const int bRow = (wn * 16 + fr) * 64;
  const unsigned short* Ar = &Al[0][0][0];
  const unsigned short* Br = &Bl[0][0][0];

  f32x4 acc[8][4];
  #pragma unroll
  for (int f = 0; f < 8; ++f)
    #pragma unroll
    for (int g = 0; g < 4; ++g)
      acc[f][g] = (f32x4){0.f, 0.f, 0.f, 0.f};

  // half-tile h: 0 = A rows 0-127, 1 = A rows 128-255, 2 = B-h0, 3 = B-h1
#define STAGE(buf, h, tn_) do {                                                        \
    const unsigned short* gs_ = ((h) < 2 ? Abase : Bbase)                              \
        + (size_t)(((h) & 1) * 128) * IN_F + (size_t)(tn_) * 64;                       \
    unsigned short* ld_ = ((h) < 2 ? Alt : Blt) + (buf) * 16384 + ((h) & 1) * 8192;    \
    gll16(ld_, gs_);                                                                   \
    gll16(ld_ + 4096, gs_ + (size_t)64 * IN_F);                                        \
  } while (0)

#define LGKMW0() do {                                                                  \
    asm volatile("s_waitcnt lgkmcnt(0)" ::: "memory");                                 \
    __builtin_amdgcn_sched_barrier(0);                                                 \
  } while (0)

#define SB() __builtin_amdgcn_sched_barrier(0)

#define BAR() do {                                                                     \
    __builtin_amdgcn_sched_barrier(0);                                                 \
    __builtin_amdgcn_s_barrier();                                                      \
    __builtin_amdgcn_sched_barrier(0);                                                 \
  } while (0)

#define RD_A(base_, mh_, f_, ks_)                                                      \
    aF[f_][ks_] = *reinterpret_cast<const bf16x8*>(                                    \
        Ar + (base_) + ((mh_) * 4 + (f_)) * 2048 + aRow + (((ks_) * 32) ^ sw0))

#define RD_B(dst_, base_, nh_, g_, ks_)                                                \
    dst_[g_][ks_] = *reinterpret_cast<const bf16x8*>(                                  \
        Br + (base_) + ((nh_) * 2 + (g_)) * 4096 + bRow + (((ks_) * 32) ^ sw0))

#define MF(mh_, nh_, f_, g_, ks_, bsrc_)                                               \
    acc[(mh_) * 4 + (f_)][(nh_) * 2 + (g_)] = __builtin_amdgcn_mfma_f32_16x16x32_bf16( \
        aF[f_][ks_], bsrc_[g_][ks_], acc[(mh_) * 4 + (f_)][(nh_) * 2 + (g_)], 0, 0, 0)

#define MF4(mh_, nh_, f_, bsrc_) do {                                                  \
    MF(mh_, nh_, f_, 0, 0, bsrc_); MF(mh_, nh_, f_, 0, 1, bsrc_);                      \
    MF(mh_, nh_, f_, 1, 0, bsrc_); MF(mh_, nh_, f_, 1, 1, bsrc_); } while (0)

  // KTILE for tile T: CC_ = T's buffer, OO_ = other. tn1_ = T+1, tn2_ = T+2.
#define KTILE(CC_, OO_, tn1_, tn2_) do {                                               \
    const int cb_ = (CC_) * 16384;                                                     \
    /* ph1: head-reads aF<-A0(T), bF0<-B0(T); stage B0(T+1)->OO; MFMA (0,0) */         \
    RD_A(cb_, 0, 0, 0); RD_A(cb_, 0, 0, 1); RD_A(cb_, 0, 1, 0); RD_A(cb_, 0, 1, 1);    \
    RD_A(cb_, 0, 2, 0); RD_A(cb_, 0, 2, 1); RD_A(cb_, 0, 3, 0); RD_A(cb_, 0, 3, 1);    \
    RD_B(bF0, cb_, 0, 0, 0); RD_B(bF0, cb_, 0, 0, 1);                                  \
    RD_B(bF0, cb_, 0, 1, 0); RD_B(bF0, cb_, 0, 1, 1);                                  \
    SB();                                                                              \
    STAGE(OO_, 2, tn1_);                                                               \
    BAR();                                                                             \
    LGKMW0();                                                                          \
    __builtin_amdgcn_s_setprio(1);                                                     \
    MF4(0, 0, 0, bF0); MF4(0, 0, 1, bF0); MF4(0, 0, 2, bF0); MF4(0, 0, 3, bF0);        \
    __builtin_amdgcn_s_setprio(0);                                                     \
    BAR();                                                                             \
    /* ph2: head-reads bF1<-B1(T); stage A0(T+2)->CC; MFMA (0,1) */                    \
    RD_B(bF1, cb_, 1, 0, 0); RD_B(bF1, cb_, 1, 0, 1);                                  \
    RD_B(bF1, cb_, 1, 1, 0); RD_B(bF1, cb_, 1, 1, 1);                                  \
    SB();                                                                              \
    STAGE(CC_, 0, tn2_);                                                               \
    BAR();                                                                             \
    LGKMW0();                                                                          \
    __builtin_amdgcn_s_setprio(1);                                                     \
    MF4(0, 1, 0, bF1); MF4(0, 1, 1, bF1); MF4(0, 1, 2, bF1); MF4(0, 1, 3, bF1);        \
    __builtin_amdgcn_s_setprio(0);                                                     \
    BAR();                                                                             \
    /* ph3: head-reads aF<-A1(T); stage B1(T+2)->CC; MFMA (1,1) */                     \
    RD_A(cb_, 1, 0, 0); RD_A(cb_, 1, 0, 1); RD_A(cb_, 1, 1, 0); RD_A(cb_, 1, 1, 1);    \
    RD_A(cb_, 1, 2, 0); RD_A(cb_, 1, 2, 1); RD_A(cb_, 1, 3, 0); RD_A(cb_, 1, 3, 1);    \
    SB();                                                                              \
    STAGE(CC_, 3, tn2_);                                                               \
    BAR();                                                                             \
    LGKMW0();                                                                          \
    __builtin_amdgcn_s_setprio(1);                                                     \
    MF4(1, 1, 0, bF1); MF4(1, 1, 1, bF1); MF4(1, 1, 2, bF1); MF4(1, 1, 3, bF1);        \
    __builtin_amdgcn_s_setprio(0);                                                     \
    BAR();                                                                             \
    /* ph4: no reads; stage A1(T+2)->CC; vmcnt(6); MFMA (1,0) */                       \
    STAGE(CC_, 1, tn2_);                                                               \
    asm volatile("s_waitcnt vmcnt(6)" ::: "memory");                                   \
    BAR();                                                                             \
    LGKMW0();                                                                          \
    __builtin_amdgcn_s_setprio(1);                                                     \
    MF4(1, 0, 0, bF0); MF4(1, 0, 1, bF0); MF4(1, 0, 2, bF0); MF4(1, 0, 3, bF0);        \
    __builtin_amdgcn_s_setprio(0);                                                     \
    BAR();                                                                             \
  } while (0)

  // prologue: steady-state issue prefix [A0(0),B1(0),A1(0),B0(0),A0(1),B1(1),
  // A1(1)]; vmcnt(6) leaves the 3 tile-1 groups outstanding -> tile 0 forced.
  STAGE(0, 0, 0);   // A0(0)
  STAGE(0, 3, 0);   // B1(0)
  STAGE(0, 1, 0);   // A1(0)
  STAGE(0, 2, 0);   // B0(0)
  STAGE(1, 0, 1);   // A0(1)
  STAGE(1, 3, 1);   // B1(1)
  STAGE(1, 1, 1);   // A1(1)
  asm volatile("s_waitcnt vmcnt(6)" ::: "memory");
  __builtin_amdgcn_s_barrier();
  __builtin_amdgcn_sched_barrier(0);

  bf16x8 aF[4][2], bF0[2][2], bF1[2][2];

  #pragma unroll 1
  for (int Th = 0; Th < 32; ++Th) {
    const int T0 = 2 * Th;
    const int e_t1 = T0 + 1;                             // <= 63 always
    const int e_t2 = (T0 + 2 < 64) ? T0 + 2 : 63;        // clamps hit dead regions
    const int o_t1 = (T0 + 2 < 64) ? T0 + 2 : 63;
    const int o_t2 = (T0 + 3 < 64) ? T0 + 3 : 63;
    KTILE(0, 1, e_t1, e_t2);
    KTILE(1, 0, o_t1, o_t2);
  }

  asm volatile("s_waitcnt vmcnt(0) lgkmcnt(0)" ::: "memory");

  // epilogue: D mapping col = lane&15, row = (lane>>4)*4 + j [m89]
  const int rsub = (lane >> 4) << 2;
  #pragma unroll
  for (int f = 0; f < 8; ++f) {
    const int row = bm * 256 + (f * 2 + wm) * 16 + rsub;
    #pragma unroll
    for (int g = 0; g < 4; ++g) {
      const int col = bn * 256 + (g * 4 + wn) * 16 + (lane & 15);
      float* op = out + (size_t)row * OUT_F + col;
      #pragma unroll
      for (int j = 0; j < 4; ++j) op[(size_t)j * OUT_F] = acc[f][g][j];
    }
  }
#undef STAGE
#undef LGKMW0
#undef SB
#undef BAR
#undef RD_A
#undef RD_B
#undef MF
#undef MF4
#undef KTILE
}

// ---------------------------------------------------------------------------
// Fallback GEMM (round-4, passing): A f32 reg-staged+converted. ws < 96MB only.
// ---------------------------------------------------------------------------
#define BM 128
#define BN 128
#define BK 32

__device__ __forceinline__ uint4 cvt8(f32x4 a, f32x4 b) {
  unsigned short o8[8] = {f2bf(a[0]), f2bf(a[1]), f2bf(a[2]), f2bf(a[3]),
                          f2bf(b[0]), f2bf(b[1]), f2bf(b[2]), f2bf(b[3])};
  return *reinterpret_cast<const uint4*>(o8);
}

__global__ __launch_bounds__(256) void gemm_f32stage(
    const float* __restrict__ X,
    const unsigned short* __restrict__ W,
    float* __restrict__ out)
{
  __shared__ __align__(16) unsigned short As[BM * BK];
  __shared__ __align__(16) unsigned short Bs[BN * BK];

  const int nbn = OUT_F / BN;
  const int cpx = (M_TOT / BM) * nbn / 8;
  const int bid = blockIdx.x;
  const int swz = (bid & 7) * cpx + (bid >> 3);
  const int bm = swz / nbn;
  const int bn = swz % nbn;

  const int tid  = threadIdx.x;
  const int lane = tid & 63;
  const int wid  = tid >> 6;
  const int wm   = wid >> 1;
  const int wn   = wid & 1;
  const int srow = tid >> 2;
  const int scol = (tid & 3) << 3;

  const float*          Ag = X + (size_t)(bm * BM + srow) * IN_F + scol;
  const unsigned short* Bg = W + (size_t)(bn * BN + srow) * IN_F + scol;

  const int fr = lane & 15;
  const int fk = (lane >> 4) << 3;

  f32x4 acc[4][4];
  #pragma unroll
  for (int m = 0; m < 4; ++m)
    #pragma unroll
    for (int n = 0; n < 4; ++n)
      acc[m][n] = (f32x4){0.f, 0.f, 0.f, 0.f};

  for (int k0 = 0; k0 < IN_F; k0 += BK) {
    const f32x4 a0a = *reinterpret_cast<const f32x4*>(Ag + k0);
    const f32x4 a0b = *reinterpret_cast<const f32x4*>(Ag + k0 + 4);
    const f32x4 a1a = *reinterpret_cast<const f32x4*>(Ag + (size_t)64 * IN_F + k0);
    const f32x4 a1b = *reinterpret_cast<const f32x4*>(Ag + (size_t)64 * IN_F + k0 + 4);
    const uint4 b0  = *reinterpret_cast<const uint4*>(Bg + k0);
    const uint4 b1  = *reinterpret_cast<const uint4*>(Bg + (size_t)64 * IN_F + k0);

    __syncthreads();
    *reinterpret_cast<uint4*>(As + tid * 8)        = cvt8(a0a, a0b);
    *reinterpret_cast<uint4*>(As + 2048 + tid * 8) = cvt8(a1a, a1b);
    *reinterpret_cast<uint4*>(Bs + tid * 8)        = b0;
    *reinterpret_cast<uint4*>(Bs + 2048 + tid * 8) = b1;
    __syncthreads();

    bf16x8 af[4], bfv[4];
    #pragma unroll
    for (int m = 0; m < 4; ++m)
      af[m] = *reinterpret_cast<const bf16x8*>(&As[(wm * 64 + m * 16 + fr) * BK + fk]);
    #pragma unroll
    for (int n = 0; n < 4; ++n)
      bfv[n] = *reinterpret_cast<const bf16x8*>(&Bs[(wn * 64 + n * 16 + fr) * BK + fk]);

    #pragma unroll
    for (int m = 0; m < 4; ++m)
      #pragma unroll
      for (int n = 0; n < 4; ++n)
        acc[m][n] = __builtin_amdgcn_mfma_f32_16x16x32_bf16(af[m], bfv[n], acc[m][n], 0, 0, 0);
  }

  const int rsub = (lane >> 4) << 2;
  #pragma unroll
  for (int m = 0; m < 4; ++m) {
    #pragma unroll
    for (int n = 0; n < 4; ++n) {
      const int col = bn * BN + wn * 64 + n * 16 + (lane & 15);
      #pragma unroll
      for (int j = 0; j < 4; ++j) {
        const int row = bm * BM + wm * 64 + m * 16 + rsub + j;
        out[(size_t)row * OUT_F + col] = acc[m][n][j];
      }
    }
  }
}

// ---------------------------------------------------------------------------
extern "C" void kernel_launch(void* const* d_in, const int* in_sizes, int n_in,
                              void* d_out, int out_size, void* d_ws, size_t ws_size,
                              hipStream_t stream) {
  (void)in_sizes; (void)n_in; (void)out_size;

  const float* x  = (const float*)d_in[0];
  const int*   qw = (const int*)d_in[1];
  const float* u  = (const float*)d_in[2];
  const float* vt = (const float*)d_in[3];
  float* out = (float*)d_out;

  unsigned short* w = (unsigned short*)d_ws;                   // 32 MB
  const size_t W_BYTES  = (size_t)OUT_F * IN_F * 2;
  const size_t XB_BYTES = (size_t)M_TOT * IN_F * 2;

  build_w<<<dim3(2048), dim3(256), 0, stream>>>(qw, u, vt, w);

  if (ws_size >= W_BYTES + XB_BYTES) {
    unsigned short* xb = w + (size_t)OUT_F * IN_F;
    convert_x<<<dim3(2048), dim3(256), 0, stream>>>(x, xb, M_TOT * IN_F / 8);
    gemm_256<<<dim3(512), dim3(512), 0, stream>>>(xb, w, out);
  } else {
    gemm_f32stage<<<dim3(2048), dim3(256), 0, stream>>>(x, w, out);
  }
}

// Round 21
// 353.542 us; speedup vs baseline: 1.0428x; 1.0170x over previous
//
#include <hip/hip_runtime.h>
#include <stdint.h>

// BitStackLinear. Device dtypes: x,u,vt = float32 (harness upcasts fp16),
// qweight = int32, out = float32.
// Pipeline (best-measured): build_w ; convert_x (ONE-SHOT, 16384 blocks,
// no loop — max TLP for the BW-bound pass) ; 256x256 4-phase Gray-code bf16
// GEMM (R13 schedule: one barrier/phase, vmcnt(4), trailing reads after
// MFMA, T2 chunk-XOR swizzle, setprio, XCD swizzle).
// Bracketing (9 GEMM variants): R9 230.8 / R13 231-233 / R10 238.5 /
// R20 249 / R18 251 / R11 268.8 / R12 445. Prep: unfused < all fusions.

#define W_BITS 4
#define OUT_F  4096
#define IN_F   4096
#define K_RANK 16
#define M_TOT  8192
#define QW_PER_BIT (OUT_F * IN_F / 8)

typedef __attribute__((ext_vector_type(8))) short bf16x8;
typedef __attribute__((ext_vector_type(4))) float f32x4;

__device__ __forceinline__ unsigned short f2bf(float f) {
  union { float f; unsigned int u; } c; c.f = f;
  unsigned int r = c.u + 0x7fffu + ((c.u >> 16) & 1u);  // RNE
  return (unsigned short)(r >> 16);
}

// ---------------------------------------------------------------------------
// Kernel 0: X f32 -> bf16, one-shot (16384 blocks x 256 thr x 8 elems)
// ---------------------------------------------------------------------------
__global__ __launch_bounds__(256) void convert_x(
    const float* __restrict__ X, unsigned short* __restrict__ Xb)
{
  const int i = blockIdx.x * 256 + threadIdx.x;   // 0 .. 4194303
  const f32x4 a = *reinterpret_cast<const f32x4*>(X + (size_t)i * 8);
  const f32x4 b = *reinterpret_cast<const f32x4*>(X + (size_t)i * 8 + 4);
  unsigned short o8[8] = {f2bf(a[0]), f2bf(a[1]), f2bf(a[2]), f2bf(a[3]),
                          f2bf(b[0]), f2bf(b[1]), f2bf(b[2]), f2bf(b[3])};
  *reinterpret_cast<uint4*>(Xb + (size_t)i * 8) = *reinterpret_cast<const uint4*>(o8);
}

// ---------------------------------------------------------------------------
// Kernel 1: w[o][i] = sum_bit sign * (u[bit] @ vt[bit])[o][i]; w bf16.
// ---------------------------------------------------------------------------
#define TO 4

__global__ __launch_bounds__(256) void build_w(
    const int*   __restrict__ qw,
    const float* __restrict__ u,
    const float* __restrict__ vt,
    unsigned short* __restrict__ w)
{
  const int tid = blockIdx.x * 256 + threadIdx.x;
  const int ig  = tid & 511;
  const int i0  = ig << 3;
  const int ob  = (tid >> 9) << 2;

  float acc[TO][8];
  #pragma unroll
  for (int t = 0; t < TO; ++t)
    #pragma unroll
    for (int ii = 0; ii < 8; ++ii) acc[t][ii] = 0.0f;

  #pragma unroll
  for (int bit = 0; bit < W_BITS; ++bit) {
    float lr[TO][8];
    #pragma unroll
    for (int t = 0; t < TO; ++t)
      #pragma unroll
      for (int ii = 0; ii < 8; ++ii) lr[t][ii] = 0.0f;

    const float* vbase = vt + (size_t)(bit * K_RANK) * IN_F + i0;
    const float* ubase = u + (size_t)(bit * OUT_F + ob) * K_RANK;

    #pragma unroll
    for (int k = 0; k < K_RANK; ++k) {
      const f32x4 v0 = *reinterpret_cast<const f32x4*>(vbase + (size_t)k * IN_F);
      const f32x4 v1 = *reinterpret_cast<const f32x4*>(vbase + (size_t)k * IN_F + 4);
      float vf[8] = {v0[0], v0[1], v0[2], v0[3], v1[0], v1[1], v1[2], v1[3]};
      #pragma unroll
      for (int t = 0; t < TO; ++t) {
        const float uk = ubase[t * K_RANK + k];
        #pragma unroll
        for (int ii = 0; ii < 8; ++ii) lr[t][ii] += uk * vf[ii];
      }
    }

    #pragma unroll
    for (int t = 0; t < TO; ++t) {
      const int q = qw[(size_t)bit * QW_PER_BIT + (size_t)(ob + t) * (IN_F / 8) + ig];
      #pragma unroll
      for (int ii = 0; ii < 8; ++ii)
        acc[t][ii] += ((q >> ii) & 1) ? lr[t][ii] : -lr[t][ii];
    }
  }

  #pragma unroll
  for (int t = 0; t < TO; ++t) {
    unsigned short o8[8];
    #pragma unroll
    for (int ii = 0; ii < 8; ++ii) o8[ii] = f2bf(acc[t][ii]);
    *reinterpret_cast<uint4*>(w + (size_t)(ob + t) * IN_F + i0) =
        *reinterpret_cast<const uint4*>(o8);
  }
}

// ---------------------------------------------------------------------------
// Kernel 2 (main, R13): 256x256 tile, BK=64, 512 thr = 8 waves (2Mx4N).
// Gray-code quadrants (0,0)->(0,1)->(1,1)->(1,0); B-reg role swap P/Q.
// Per phase (ONE barrier): STAGE ; vmcnt(4)+barrier ; lgkm(0) ; setprio+MFMA ;
// trailing ds_reads for the NEXT phase. Stage order ph1:B0' ph2:A0' ph3:B1'
// ph4:A1'; every phase-end read targets the G_{p-2} group (landed by vmcnt(4)
// + barrier). WAR separated by >= 2 barriers everywhere.
// ---------------------------------------------------------------------------
__device__ __forceinline__ void gll16(unsigned short* lds, const unsigned short* g) {
  __builtin_amdgcn_global_load_lds(
      (const __attribute__((address_space(1))) unsigned int*)g,
      (__attribute__((address_space(3))) unsigned int*)lds,
      16, 0, 0);
}

__global__ __launch_bounds__(512, 2) void gemm_256(
    const unsigned short* __restrict__ X,    // [M_TOT][IN_F] bf16
    const unsigned short* __restrict__ W,    // [OUT_F][IN_F] bf16
    float* __restrict__ out)                 // [M_TOT][OUT_F] f32
{
  __shared__ __align__(16) unsigned short Al[2][256][64];   // 64 KiB
  __shared__ __align__(16) unsigned short Bl[2][256][64];   // 64 KiB

  const int bid = blockIdx.x;                   // 512 blocks (32 x 16)
  const int swz = (bid & 7) * 64 + (bid >> 3);  // XCD-bijective (512%8==0)
  const int bm = swz >> 4;                      // 0..31
  const int bn = swz & 15;                      // 0..15

  const int tid  = threadIdx.x;
  const int lane = tid & 63;
  const int wid  = tid >> 6;     // 0..7
  const int wm   = wid >> 2;     // 0..1
  const int wn   = wid & 3;      // 0..3

  // staging: row sr, physical chunk tid&7 holds logical chunk (tid&7)^(sr&7)
  const int sr = tid >> 3;                                  // 0..63
  const int sc = (((tid & 7) ^ (sr & 7)) << 3);             // shorts

  const unsigned short* Abase = X + (size_t)(bm * 256 + sr) * IN_F + sc;
  const unsigned short* Bbase = W + (size_t)(bn * 256 + sr) * IN_F + sc;
  unsigned short* Alt = &Al[0][0][0] + tid * 8;   // linear dest
  unsigned short* Blt = &Bl[0][0][0] + tid * 8;

  // fragment reads (mfma_f32_16x16x32_bf16: lane l -> row l&15, k=(l>>4)*8..+7)
  const int fr  = lane & 15;
  const int sw0 = (((lane >> 4) ^ (fr & 7)) << 3);   // shorts; ks=1 adds ^32
  const int aRow = (wm * 16 + fr) * 64;
  const int bRow = (wn * 16 + fr) * 64;
  const unsigned short* Ar = &Al[0][0][0];
  const unsigned short* Br = &Bl[0][0][0];

  f32x4 acc[8][4];
  #pragma unroll
  for (int f = 0; f < 8; ++f)
    #pragma unroll
    for (int g = 0; g < 4; ++g)
      acc[f][g] = (f32x4){0.f, 0.f, 0.f, 0.f};

  // half-tile h: 0 = A rows 0-127, 1 = A rows 128-255, 2 = B-h0, 3 = B-h1
#define STAGE(buf, h, tn_) do {                                                        \
    const unsigned short* gs_ = ((h) < 2 ? Abase : Bbase)                              \
        + (size_t)(((h) & 1) * 128) * IN_F + (size_t)(tn_) * 64;                       \
    unsigned short* ld_ = ((h) < 2 ? Alt : Blt) + (buf) * 16384 + ((h) & 1) * 8192;    \
    gll16(ld_, gs_);                                                                   \
    gll16(ld_ + 4096, gs_ + (size_t)64 * IN_F);                                        \
  } while (0)

#define WAITBAR() do {                                                                 \
    asm volatile("s_waitcnt vmcnt(4)" ::: "memory");                                   \
    __builtin_amdgcn_s_barrier();                                                      \
    __builtin_amdgcn_sched_barrier(0);                                                 \
  } while (0)

#define LGKMW(n_) do {                                                                 \
    asm volatile("s_waitcnt lgkmcnt(" #n_ ")" ::: "memory");                           \
    __builtin_amdgcn_sched_barrier(0);                                                 \
  } while (0)

#define SB() __builtin_amdgcn_sched_barrier(0)

#define RD_A(base_, mh_, f_, ks_)                                                      \
    aF[f_][ks_] = *reinterpret_cast<const bf16x8*>(                                    \
        Ar + (base_) + ((mh_) * 4 + (f_)) * 2048 + aRow + (((ks_) * 32) ^ sw0))

#define RD_B(dst_, base_, nh_, g_, ks_)                                                \
    dst_[g_][ks_] = *reinterpret_cast<const bf16x8*>(                                  \
        Br + (base_) + ((nh_) * 2 + (g_)) * 4096 + bRow + (((ks_) * 32) ^ sw0))

#define MF(mh_, nh_, f_, g_, ks_, bsrc_)                                               \
    acc[(mh_) * 4 + (f_)][(nh_) * 2 + (g_)] = __builtin_amdgcn_mfma_f32_16x16x32_bf16( \
        aF[f_][ks_], bsrc_[g_][ks_], acc[(mh_) * 4 + (f_)][(nh_) * 2 + (g_)], 0, 0, 0)

#define MF4(mh_, nh_, f_, bsrc_) do {                                                  \
    MF(mh_, nh_, f_, 0, 0, bsrc_); MF(mh_, nh_, f_, 0, 1, bsrc_);                      \
    MF(mh_, nh_, f_, 1, 0, bsrc_); MF(mh_, nh_, f_, 1, 1, bsrc_); } while (0)

#define KTILE(P_, Q_, CC_, OO_, tn_) do {                                              \
    const int cb_ = (CC_) * 16384, ob_ = (OO_) * 16384;                                \
    /* ph1: MFMA (0,0)=A0xP; trailing reads Q<-B1(cur). Stage B0'(next). */            \
    STAGE(OO_, 2, tn_);                                                                \
    WAITBAR();                                                                         \
    LGKMW(0);                                                                          \
    __builtin_amdgcn_s_setprio(1);                                                     \
    MF4(0, 0, 0, P_); MF4(0, 0, 1, P_); MF4(0, 0, 2, P_); MF4(0, 0, 3, P_);            \
    __builtin_amdgcn_s_setprio(0);                                                     \
    SB();                                                                              \
    RD_B(Q_, cb_, 1, 0, 0); RD_B(Q_, cb_, 1, 0, 1);                                    \
    RD_B(Q_, cb_, 1, 1, 0); RD_B(Q_, cb_, 1, 1, 1);                                    \
    /* ph2: MFMA (0,1)=A0xQ; trailing reads aF<-A1(cur). Stage A0'(next). */           \
    STAGE(OO_, 0, tn_);                                                                \
    WAITBAR();                                                                         \
    LGKMW(0);                                                                          \
    __builtin_amdgcn_s_setprio(1);                                                     \
    MF4(0, 1, 0, Q_); MF4(0, 1, 1, Q_); MF4(0, 1, 2, Q_); MF4(0, 1, 3, Q_);            \
    __builtin_amdgcn_s_setprio(0);                                                     \
    SB();                                                                              \
    RD_A(cb_, 1, 0, 0); RD_A(cb_, 1, 0, 1); RD_A(cb_, 1, 1, 0); RD_A(cb_, 1, 1, 1);    \
    RD_A(cb_, 1, 2, 0); RD_A(cb_, 1, 2, 1); RD_A(cb_, 1, 3, 0); RD_A(cb_, 1, 3, 1);    \
    /* ph3: MFMA (1,1)=A1xQ; trailing reads Q<-B0(next). Stage B1'(next). */           \
    STAGE(OO_, 3, tn_);                                                                \
    WAITBAR();                                                                         \
    LGKMW(0);                                                                          \
    __builtin_amdgcn_s_setprio(1);                                                     \
    MF4(1, 1, 0, Q_); MF4(1, 1, 1, Q_); MF4(1, 1, 2, Q_); MF4(1, 1, 3, Q_);            \
    __builtin_amdgcn_s_setprio(0);                                                     \
    SB();                                                                              \
    RD_B(Q_, ob_, 0, 0, 0); RD_B(Q_, ob_, 0, 0, 1);                                    \
    RD_B(Q_, ob_, 0, 1, 0); RD_B(Q_, ob_, 0, 1, 1);                                    \
    /* ph4: MFMA (1,0)=A1xP; trailing reads aF<-A0(next). Stage A1'(next). */          \
    STAGE(OO_, 1, tn_);                                                                \
    WAITBAR();                                                                         \
    LGKMW(0);                                                                          \
    __builtin_amdgcn_s_setprio(1);                                                     \
    MF4(1, 0, 0, P_); MF4(1, 0, 1, P_); MF4(1, 0, 2, P_); MF4(1, 0, 3, P_);            \
    __builtin_amdgcn_s_setprio(0);                                                     \
    SB();                                                                              \
    RD_A(ob_, 0, 0, 0); RD_A(ob_, 0, 0, 1); RD_A(ob_, 0, 1, 0); RD_A(ob_, 0, 1, 1);    \
    RD_A(ob_, 0, 2, 0); RD_A(ob_, 0, 2, 1); RD_A(ob_, 0, 3, 0); RD_A(ob_, 0, 3, 1);    \
  } while (0)

  // prologue: stage tile 0 (A0, B0, B1, A1); vmcnt(4) -> A0,B0 landed;
  // barrier; pre-read aF<-A0, bF0<-B0.
  STAGE(0, 0, 0);
  STAGE(0, 2, 0);
  STAGE(0, 3, 0);
  STAGE(0, 1, 0);
  asm volatile("s_waitcnt vmcnt(4)" ::: "memory");
  __builtin_amdgcn_s_barrier();
  __builtin_amdgcn_sched_barrier(0);

  bf16x8 aF[4][2], bF0[2][2], bF1[2][2];
  RD_A(0, 0, 0, 0); RD_A(0, 0, 0, 1); RD_A(0, 0, 1, 0); RD_A(0, 0, 1, 1);
  RD_A(0, 0, 2, 0); RD_A(0, 0, 2, 1); RD_A(0, 0, 3, 0); RD_A(0, 0, 3, 1);
  RD_B(bF0, 0, 0, 0, 0); RD_B(bF0, 0, 0, 0, 1);
  RD_B(bF0, 0, 0, 1, 0); RD_B(bF0, 0, 0, 1, 1);

  #pragma unroll 1
  for (int Th = 0; Th < 32; ++Th) {
    const int T0 = 2 * Th;
    const int tnA = T0 + 1;                          // <= 63 always
    const int tnB = (T0 + 2 < 64) ? T0 + 2 : 63;     // clamp (dup, unread)
    KTILE(bF0, bF1, 0, 1, tnA);
    KTILE(bF1, bF0, 1, 0, tnB);
  }

  asm volatile("s_waitcnt vmcnt(0) lgkmcnt(0)" ::: "memory");

  // epilogue: D mapping col = lane&15, row = (lane>>4)*4 + j [m89]
  const int rsub = (lane >> 4) << 2;
  #pragma unroll
  for (int f = 0; f < 8; ++f) {
    const int row = bm * 256 + (f * 2 + wm) * 16 + rsub;
    #pragma unroll
    for (int g = 0; g < 4; ++g) {
      const int col = bn * 256 + (g * 4 + wn) * 16 + (lane & 15);
      float* op = out + (size_t)row * OUT_F + col;
      #pragma unroll
      for (int j = 0; j < 4; ++j) op[(size_t)j * OUT_F] = acc[f][g][j];
    }
  }
#undef STAGE
#undef WAITBAR
#undef LGKMW
#undef SB
#undef RD_A
#undef RD_B
#undef MF
#undef MF4
#undef KTILE
}

// ---------------------------------------------------------------------------
// Fallback GEMM (round-4, passing): A f32 reg-staged+converted. ws < 96MB only.
// ---------------------------------------------------------------------------
#define BM 128
#define BN 128
#define BK 32

__device__ __forceinline__ uint4 cvt8(f32x4 a, f32x4 b) {
  unsigned short o8[8] = {f2bf(a[0]), f2bf(a[1]), f2bf(a[2]), f2bf(a[3]),
                          f2bf(b[0]), f2bf(b[1]), f2bf(b[2]), f2bf(b[3])};
  return *reinterpret_cast<const uint4*>(o8);
}

__global__ __launch_bounds__(256) void gemm_f32stage(
    const float* __restrict__ X,
    const unsigned short* __restrict__ W,
    float* __restrict__ out)
{
  __shared__ __align__(16) unsigned short As[BM * BK];
  __shared__ __align__(16) unsigned short Bs[BN * BK];

  const int nbn = OUT_F / BN;
  const int cpx = (M_TOT / BM) * nbn / 8;
  const int bid = blockIdx.x;
  const int swz = (bid & 7) * cpx + (bid >> 3);
  const int bm = swz / nbn;
  const int bn = swz % nbn;

  const int tid  = threadIdx.x;
  const int lane = tid & 63;
  const int wid  = tid >> 6;
  const int wm   = wid >> 1;
  const int wn   = wid & 1;
  const int srow = tid >> 2;
  const int scol = (tid & 3) << 3;

  const float*          Ag = X + (size_t)(bm * BM + srow) * IN_F + scol;
  const unsigned short* Bg = W + (size_t)(bn * BN + srow) * IN_F + scol;

  const int fr = lane & 15;
  const int fk = (lane >> 4) << 3;

  f32x4 acc[4][4];
  #pragma unroll
  for (int m = 0; m < 4; ++m)
    #pragma unroll
    for (int n = 0; n < 4; ++n)
      acc[m][n] = (f32x4){0.f, 0.f, 0.f, 0.f};

  for (int k0 = 0; k0 < IN_F; k0 += BK) {
    const f32x4 a0a = *reinterpret_cast<const f32x4*>(Ag + k0);
    const f32x4 a0b = *reinterpret_cast<const f32x4*>(Ag + k0 + 4);
    const f32x4 a1a = *reinterpret_cast<const f32x4*>(Ag + (size_t)64 * IN_F + k0);
    const f32x4 a1b = *reinterpret_cast<const f32x4*>(Ag + (size_t)64 * IN_F + k0 + 4);
    const uint4 b0  = *reinterpret_cast<const uint4*>(Bg + k0);
    const uint4 b1  = *reinterpret_cast<const uint4*>(Bg + (size_t)64 * IN_F + k0);

    __syncthreads();
    *reinterpret_cast<uint4*>(As + tid * 8)        = cvt8(a0a, a0b);
    *reinterpret_cast<uint4*>(As + 2048 + tid * 8) = cvt8(a1a, a1b);
    *reinterpret_cast<uint4*>(Bs + tid * 8)        = b0;
    *reinterpret_cast<uint4*>(Bs + 2048 + tid * 8) = b1;
    __syncthreads();

    bf16x8 af[4], bfv[4];
    #pragma unroll
    for (int m = 0; m < 4; ++m)
      af[m] = *reinterpret_cast<const bf16x8*>(&As[(wm * 64 + m * 16 + fr) * BK + fk]);
    #pragma unroll
    for (int n = 0; n < 4; ++n)
      bfv[n] = *reinterpret_cast<const bf16x8*>(&Bs[(wn * 64 + n * 16 + fr) * BK + fk]);

    #pragma unroll
    for (int m = 0; m < 4; ++m)
      #pragma unroll
      for (int n = 0; n < 4; ++n)
        acc[m][n] = __builtin_amdgcn_mfma_f32_16x16x32_bf16(af[m], bfv[n], acc[m][n], 0, 0, 0);
  }

  const int rsub = (lane >> 4) << 2;
  #pragma unroll
  for (int m = 0; m < 4; ++m) {
    #pragma unroll
    for (int n = 0; n < 4; ++n) {
      const int col = bn * BN + wn * 64 + n * 16 + (lane & 15);
      #pragma unroll
      for (int j = 0; j < 4; ++j) {
        const int row = bm * BM + wm * 64 + m * 16 + rsub + j;
        out[(size_t)row * OUT_F + col] = acc[m][n][j];
      }
    }
  }
}

// ---------------------------------------------------------------------------
extern "C" void kernel_launch(void* const* d_in, const int* in_sizes, int n_in,
                              void* d_out, int out_size, void* d_ws, size_t ws_size,
                              hipStream_t stream) {
  (void)in_sizes; (void)n_in; (void)out_size;

  const float* x  = (const float*)d_in[0];
  const int*   qw = (const int*)d_in[1];
  const float* u  = (const float*)d_in[2];
  const float* vt = (const float*)d_in[3];
  float* out = (float*)d_out;

  unsigned short* w = (unsigned short*)d_ws;                   // 32 MB
  const size_t W_BYTES  = (size_t)OUT_F * IN_F * 2;
  const size_t XB_BYTES = (size_t)M_TOT * IN_F * 2;

  build_w<<<dim3(2048), dim3(256), 0, stream>>>(qw, u, vt, w);

  if (ws_size >= W_BYTES + XB_BYTES) {
    unsigned short* xb = w + (size_t)OUT_F * IN_F;
    // one-shot: 33.55M elems / 8 per thread / 256 per block = 16384 blocks
    convert_x<<<dim3(16384), dim3(256), 0, stream>>>(x, xb);
    gemm_256<<<dim3(512), dim3(512), 0, stream>>>(xb, w, out);
  } else {
    gemm_f32stage<<<dim3(2048), dim3(256), 0, stream>>>(x, w, out);
  }
}